// Round 8
// baseline (211.733 us; speedup 1.0000x reference)
//
#include <hip/hip_runtime.h>
#include <math.h>

// Problem constants (B=4, S=2048, H=1024, E=16, TOP_K=4)
constexpr int kTokens = 8192;   // B*S
constexpr int kH      = 1024;
constexpr int kE      = 16;
constexpr int kTopK   = 4;

// ---------------------------------------------------------------------------
// Stage 1 v8: NO scalar loads in the loop (R4/R7's limiter: 8 s_loadx16/pass
// over the 112-SGPR budget -> rolled into load->lgkmcnt(0)->fmac round-trips,
// and SMEM shares lgkmcnt with DS out-of-order -> full drains, VALUBusy 17%).
// Weights are per-lane VECTOR loads: lane = (tq = ln>>2, eq = ln&3) owns
// 4 tokens x experts [eq*4,eq*4+4). Per h: one global dwordx4 of W[h][eq*4..]
// = 4 distinct 16-B segs in ONE 64-B line = 1 L1 transaction, vmcnt-tracked
// (no cross-pipe drains). Compute:weight = 512 fmac-cyc : 16 loads per pass.
// Block = 256 thr / 4 waves = 256 tokens x one 128-k slice (NC=32 slices of
// the 4096 k-columns). Grid = 32 tg x 32 ks = 1024 blocks = 4096 waves
// (4/SIMD, 2x R4). x tile [256 tok][16 h] double-buffered in LDS (stride 20
// floats: 2-way read aliasing = free), register-prefetch + 1 barrier/pass.
// Numerics: fp32 accum per 128-k slice (err ~3e-7), fp64 combine of the 32
// slices in stage 2 -- same order as the 7 passing rounds.
// ---------------------------------------------------------------------------
template<int NC>
__global__ __launch_bounds__(256, 4)
void router_fmac(const float* __restrict__ x,   const float* __restrict__ img,
                 const float* __restrict__ txt, const float* __restrict__ aud,
                 const float* __restrict__ Wg,  const float* __restrict__ Wi,
                 const float* __restrict__ Wt,  const float* __restrict__ Wa,
                 float* __restrict__ partials)
{
    constexpr int KEXT = 4096 / NC;      // k-columns per block (128 @ NC=32)
    constexpr int P    = KEXT / 16;      // passes of 16 h
    constexpr int MS   = NC / 4;         // slices per modality

    __shared__ float xt[2][256 * 20];    // 2 x 20 KB, stride 20 (16B-aligned)

    const int t   = threadIdx.x;
    const int w   = t >> 6;              // wave 0..3
    const int ln  = t & 63;
    const int tq  = ln >> 2;             // token slot 0..15
    const int eq  = ln & 3;              // e-quad 0..3
    const int bid = blockIdx.x;
    const int ks  = bid & (NC - 1);      // k-slice (fast digit, as R4)
    const int tg  = bid / NC;            // token group
    const int m   = ks / MS;             // modality
    const int h0  = (ks % MS) * KEXT;    // h offset within modality
    const int tok0 = tg * 256;

    const float* Xm = (m == 0) ? x  : (m == 1) ? img : (m == 2) ? txt : aud;
    const float* Wm = (m == 0) ? Wg : (m == 1) ? Wi  : (m == 2) ? Wt  : Wa;

    // staging roles: sr = row base 0..63 (rows sr+64i), sc = float4 col of 16 h
    const int sc = t & 3;
    const int sr = t >> 2;
    const float* gbase = Xm + (size_t)tok0 * kH + h0 + sc * 4;

    float4 pf[4];

    // ---- prologue: stage pass 0 ----
#pragma unroll
    for (int i = 0; i < 4; ++i)
        pf[i] = *(const float4*)(gbase + (size_t)(sr + 64 * i) * kH);
#pragma unroll
    for (int i = 0; i < 4; ++i)
        *(float4*)&xt[0][(sr + 64 * i) * 20 + sc * 4] = pf[i];
    __syncthreads();

    float facc[4][4];
#pragma unroll
    for (int i = 0; i < 4; ++i)
#pragma unroll
        for (int q = 0; q < 4; ++q) facc[i][q] = 0.f;

    const int r0 = w * 64 + tq;          // lane's token rows: r0 + 16i

#pragma unroll
    for (int p = 0; p < P; ++p) {
        // prefetch next pass's x into registers (in flight during compute)
        if (p < P - 1) {
#pragma unroll
            for (int i = 0; i < 4; ++i)
                pf[i] = *(const float4*)(gbase + (size_t)(sr + 64 * i) * kH + (p + 1) * 16);
        }

        const float* buf = xt[p & 1];
        const float* wp  = Wm + (size_t)(h0 + p * 16) * kE + eq * 4;

#pragma unroll
        for (int hg = 0; hg < 4; ++hg) {     // 4-h groups
            float4 wv[4];
#pragma unroll
            for (int j = 0; j < 4; ++j)      // 1 line/instr, vmcnt-tracked
                wv[j] = *(const float4*)(wp + (hg * 4 + j) * kE);
            float4 xv[4];
#pragma unroll
            for (int i = 0; i < 4; ++i)
                xv[i] = *(const float4*)&buf[(r0 + 16 * i) * 20 + hg * 4];
#pragma unroll
            for (int j = 0; j < 4; ++j) {
#pragma unroll
                for (int i = 0; i < 4; ++i) {
                    const float xh = (j == 0) ? xv[i].x : (j == 1) ? xv[i].y
                                   : (j == 2) ? xv[i].z : xv[i].w;
                    facc[i][0] += xh * wv[j].x;  facc[i][1] += xh * wv[j].y;
                    facc[i][2] += xh * wv[j].z;  facc[i][3] += xh * wv[j].w;
                }
            }
        }

        if (p < P - 1) {
#pragma unroll
            for (int i = 0; i < 4; ++i)
                *(float4*)&xt[(p + 1) & 1][(sr + 64 * i) * 20 + sc * 4] = pf[i];
        }
        __syncthreads();
    }

    // ---- epilogue: fp32 partial [ks][tok][e]; 16 tok x 64 B contiguous ----
#pragma unroll
    for (int i = 0; i < 4; ++i) {
        const int token = tok0 + w * 64 + tq + 16 * i;
        *(float4*)&partials[((size_t)ks * kTokens + token) * kE + eq * 4] =
            make_float4(facc[i][0], facc[i][1], facc[i][2], facc[i][3]);
    }
}

// ---------------------------------------------------------------------------
// Stage 2: combine NC slice-partials + biases (fp64), softmax, top-k, output
// writes, per-block expert sums. Block = 64 tokens x 256 threads.
// ---------------------------------------------------------------------------
template<int NC>
__global__ __launch_bounds__(256)
void router_topk(const float* __restrict__ partials,
                 const float* __restrict__ bg, const float* __restrict__ bi,
                 const float* __restrict__ bt, const float* __restrict__ ba,
                 float* __restrict__ out, float* __restrict__ blocksum)
{
    __shared__ double lgs[64][kE + 1];
    __shared__ float  pr[64][kE + 1];

    const int t    = threadIdx.x;
    const int tq   = t >> 2;      // token offset 0..63
    const int eq   = t & 3;       // e-quad
    const int tok0 = blockIdx.x * 64;

    double a0 = (double)bg[eq*4+0] + (double)bi[eq*4+0] + (double)bt[eq*4+0] + (double)ba[eq*4+0];
    double a1 = (double)bg[eq*4+1] + (double)bi[eq*4+1] + (double)bt[eq*4+1] + (double)ba[eq*4+1];
    double a2 = (double)bg[eq*4+2] + (double)bi[eq*4+2] + (double)bt[eq*4+2] + (double)ba[eq*4+2];
    double a3 = (double)bg[eq*4+3] + (double)bi[eq*4+3] + (double)bt[eq*4+3] + (double)ba[eq*4+3];

#pragma unroll
    for (int c = 0; c < NC; ++c) {
        const float4 v = *(const float4*)(partials + ((size_t)c * kTokens + tok0 + tq) * kE + eq * 4);
        a0 += (double)v.x;  a1 += (double)v.y;  a2 += (double)v.z;  a3 += (double)v.w;
    }
    lgs[tq][eq*4+0] = a0;  lgs[tq][eq*4+1] = a1;
    lgs[tq][eq*4+2] = a2;  lgs[tq][eq*4+3] = a3;
    __syncthreads();

    if (t < 64) {
        const int tok = tok0 + t;
        double lg[kE];
#pragma unroll
        for (int e = 0; e < kE; ++e) lg[e] = lgs[t][e];

        double mx = lg[0];
#pragma unroll
        for (int e = 1; e < kE; ++e) mx = fmax(mx, lg[e]);

        float p[kE];
        float sum = 0.f;
#pragma unroll
        for (int e = 0; e < kE; ++e) {
            p[e] = expf((float)(lg[e] - mx));
            sum += p[e];
        }
        const float inv = 1.f / sum;
#pragma unroll
        for (int e = 0; e < kE; ++e) { p[e] *= inv; pr[t][e] = p[e]; }

        // top-4, descending, ties -> smallest index (matches jax.lax.top_k)
        unsigned used = 0;
        float tp[kTopK];
        int   ti[kTopK];
        float s4 = 0.f;
#pragma unroll
        for (int k = 0; k < kTopK; ++k) {
            float best = -1.f;
            int   bidx = 0;
#pragma unroll
            for (int e = 0; e < kE; ++e) {
                if (!((used >> e) & 1u) && p[e] > best) { best = p[e]; bidx = e; }
            }
            used |= 1u << bidx;
            tp[k] = best;
            ti[k] = bidx;
            s4 += best;
        }
        const float rn = 1.f / s4;

        *(float4*)&out[(size_t)tok * kTopK] =
            make_float4((float)ti[0], (float)ti[1], (float)ti[2], (float)ti[3]);
        *(float4*)&out[(size_t)kTokens * kTopK + (size_t)tok * kTopK] =
            make_float4(tp[0] * rn, tp[1] * rn, tp[2] * rn, tp[3] * rn);
    }
    __syncthreads();

    if (t < kE) {
        float s = 0.f;
#pragma unroll
        for (int tk = 0; tk < 64; ++tk) s += pr[tk][t];
        blocksum[blockIdx.x * kE + t] = s;
    }
}

// ---------------------------------------------------------------------------
// Stage 3: 128 block-partials -> mean prob per expert -> aux loss scalar
// ---------------------------------------------------------------------------
__global__ __launch_bounds__(64)
void router_aux(const float* __restrict__ blocksum, float* __restrict__ out)
{
    __shared__ double ps[kE];
    const int t = threadIdx.x;
    if (t < kE) {
        double s = 0.0;
        for (int b = 0; b < 128; ++b) s += (double)blocksum[b * kE + t];
        ps[t] = s / (double)kTokens;
    }
    __syncthreads();
    if (t == 0) {
        double aux = 0.0;
#pragma unroll
        for (int e = 0; e < kE; ++e) aux += ps[e] * log(ps[e] * (double)kE + 1e-9);
        out[(size_t)kTokens * kTopK * 2] = (float)aux;  // element 65536
    }
}

extern "C" void kernel_launch(void* const* d_in, const int* in_sizes, int n_in,
                              void* d_out, int out_size, void* d_ws, size_t ws_size,
                              hipStream_t stream)
{
    const float* x   = (const float*)d_in[0];
    const float* img = (const float*)d_in[1];
    const float* txt = (const float*)d_in[2];
    const float* aud = (const float*)d_in[3];
    const float* Wg  = (const float*)d_in[4];
    const float* bg  = (const float*)d_in[5];
    const float* Wi  = (const float*)d_in[6];
    const float* bi  = (const float*)d_in[7];
    const float* Wt  = (const float*)d_in[8];
    const float* bt  = (const float*)d_in[9];
    const float* Wa  = (const float*)d_in[10];
    const float* ba  = (const float*)d_in[11];

    float* out = (float*)d_out;

    const size_t need32 = (size_t)32 * kTokens * kE * 4 + 128 * kE * 4;  // 16.8 MB
    if (ws_size >= need32) {
        float* partials = (float*)d_ws;
        float* blocksum = (float*)((char*)d_ws + (size_t)32 * kTokens * kE * 4);
        router_fmac<32><<<1024, 256, 0, stream>>>(x, img, txt, aud, Wg, Wi, Wt, Wa, partials);
        router_topk<32><<<128, 256, 0, stream>>>(partials, bg, bi, bt, ba, out, blocksum);
        router_aux<<<1, 64, 0, stream>>>(blocksum, out);
    } else {
        float* partials = (float*)d_ws;                                  // 8.4 MB (proven fits)
        float* blocksum = (float*)((char*)d_ws + (size_t)16 * kTokens * kE * 4);
        router_fmac<16><<<512, 256, 0, stream>>>(x, img, txt, aud, Wg, Wi, Wt, Wa, partials);
        router_topk<16><<<128, 256, 0, stream>>>(partials, bg, bi, bt, ba, out, blocksum);
        router_aux<<<1, 64, 0, stream>>>(blocksum, out);
    }
}